// Round 2
// baseline (325.951 us; speedup 1.0000x reference)
//
#include <hip/hip_runtime.h>

typedef __bf16 bf16x8 __attribute__((ext_vector_type(8)));
typedef float floatx4 __attribute__((ext_vector_type(4)));

#define MFMA(a, b, c) __builtin_amdgcn_mfma_f32_16x16x32_bf16(a, b, c, 0, 0, 0)

#define BNS 0.9999950000374997f  /* 1/sqrt(1+1e-5) */
#define LRELU(x) ((x) > 0.f ? (x) : 0.01f * (x))
#define SIMS 136  /* 128 + 8 pad, keeps 16B alignment, spreads banks */
#define HBS 72    /* 64 + 8 pad */

// ---------------------------------------------------------------------------
// k_init: copy fp32 ep0 -> mutable fp32 working buffer (ws is poisoned 0xAA)
// ---------------------------------------------------------------------------
__global__ __launch_bounds__(256) void k_init(const float* __restrict__ ep0,
                                              float* __restrict__ ep) {
  const int idx = blockIdx.x * 256 + threadIdx.x;
  ep[idx] = ep0[idx];
}

// ---------------------------------------------------------------------------
// k_psim: one WG per (b,i) row. Fuses: sim features, 128->256->128->1 MLP
// (bf16 MFMA, fp32 weights converted at fragment build), sigmoid, ep-masking,
// top-k, l1norm, +eye, row-normalize. In-place ep row update; optional fp32
// output write (final generation).
// ---------------------------------------------------------------------------
__global__ void __launch_bounds__(256, 2)
k_psim(const float* __restrict__ vp, float* __restrict__ ep,
       const float* __restrict__ w1, const float* __restrict__ w2,
       const float* __restrict__ w3, const float* __restrict__ b3,
       int kval, float* __restrict__ outp) {
  __shared__ __bf16 sim[128 * SIMS];   // A-tile for matmul1; later reused for h2
  __shared__ __bf16 hbuf[128 * HBS];   // 64-col quarter of hidden layer h1
  __shared__ float ep_row[128];
  __shared__ float e_row[128];
  __shared__ float e_m[128];
  __shared__ float red[256];

  const int tid = threadIdx.x;
  const int b = blockIdx.x >> 7, i = blockIdx.x & 127;
  const float* vpb = vp + ((size_t)b << 14);
  const float* vpi = vpb + (i << 7);
  const size_t rowoff = ((size_t)blockIdx.x) << 7;

  // ---- Phase A: sim[j][c] = (vp[i][c]-vp[j][c])^2 (bf16), load ep row ----
  {
    const int j = tid >> 1;
    const int c0 = (tid & 1) << 6;
    const float* vpj = vpb + (j << 7) + c0;
    const float* vpx = vpi + c0;
#pragma unroll
    for (int c = 0; c < 64; c += 8) {
      float4 a0 = *(const float4*)(vpj + c);
      float4 a1 = *(const float4*)(vpj + c + 4);
      float4 b0 = *(const float4*)(vpx + c);
      float4 b1 = *(const float4*)(vpx + c + 4);
      bf16x8 t;
      float d;
      d = a0.x - b0.x; t[0] = (__bf16)(d * d);
      d = a0.y - b0.y; t[1] = (__bf16)(d * d);
      d = a0.z - b0.z; t[2] = (__bf16)(d * d);
      d = a0.w - b0.w; t[3] = (__bf16)(d * d);
      d = a1.x - b1.x; t[4] = (__bf16)(d * d);
      d = a1.y - b1.y; t[5] = (__bf16)(d * d);
      d = a1.z - b1.z; t[6] = (__bf16)(d * d);
      d = a1.w - b1.w; t[7] = (__bf16)(d * d);
      *(bf16x8*)&sim[j * SIMS + c0 + c] = t;
    }
    if (tid < 128) ep_row[tid] = (tid == i) ? 0.f : ep[rowoff + tid];
  }
  __syncthreads();

  const int wv = tid >> 6;   // wave 0..3
  const int ln = tid & 63;
  const int qd = ln >> 4;    // quad 0..3
  const int cc = ln & 15;

  floatx4 acc2[8][2];
#pragma unroll
  for (int m = 0; m < 8; m++) {
    acc2[m][0] = (floatx4){0.f, 0.f, 0.f, 0.f};
    acc2[m][1] = (floatx4){0.f, 0.f, 0.f, 0.f};
  }

  // ---- MLP: four 64-col quarters of h1; matmul2 accumulates across them ----
  for (int qtr = 0; qtr < 4; qtr++) {
    // matmul1 quarter: h1[:, qtr*64 .. +64) ; wave owns 16 cols
    bf16x8 bw[4];
#pragma unroll
    for (int kt = 0; kt < 4; kt++) {
      bf16x8 f;
      const float* wp = w1 + (size_t)(kt * 32 + qd * 8) * 256 + qtr * 64 + wv * 16 + cc;
#pragma unroll
      for (int jj = 0; jj < 8; jj++) f[jj] = (__bf16)wp[jj * 256];
      bw[kt] = f;
    }
#pragma unroll
    for (int m2 = 0; m2 < 8; m2 += 2) {  // two m-tiles in flight for MFMA ILP
      bf16x8 af0[4], af1[4];
#pragma unroll
      for (int kt = 0; kt < 4; kt++) {
        af0[kt] = *(const bf16x8*)&sim[(m2 * 16 + cc) * SIMS + kt * 32 + qd * 8];
        af1[kt] = *(const bf16x8*)&sim[((m2 + 1) * 16 + cc) * SIMS + kt * 32 + qd * 8];
      }
      floatx4 x0 = (floatx4){0.f, 0.f, 0.f, 0.f};
      floatx4 x1 = (floatx4){0.f, 0.f, 0.f, 0.f};
#pragma unroll
      for (int kt = 0; kt < 4; kt++) {
        x0 = MFMA(af0[kt], bw[kt], x0);
        x1 = MFMA(af1[kt], bw[kt], x1);
      }
#pragma unroll
      for (int r = 0; r < 4; r++) {
        float v0 = x0[r] * BNS;
        float v1 = x1[r] * BNS;
        hbuf[(m2 * 16 + qd * 4 + r) * HBS + wv * 16 + cc] = (__bf16)LRELU(v0);
        hbuf[((m2 + 1) * 16 + qd * 4 + r) * HBS + wv * 16 + cc] = (__bf16)LRELU(v1);
      }
    }
    __syncthreads();

    // matmul2 partial: acc2 += hbuf(128x64) @ w2[qtr*64..+64, :] ; wave owns 32 cols
    bf16x8 bw2[2][2];
#pragma unroll
    for (int nt = 0; nt < 2; nt++)
#pragma unroll
      for (int kt = 0; kt < 2; kt++) {
        bf16x8 f;
        const float* wp = w2 + (size_t)(qtr * 64 + kt * 32 + qd * 8) * 128 + wv * 32 + nt * 16 + cc;
#pragma unroll
        for (int jj = 0; jj < 8; jj++) f[jj] = (__bf16)wp[jj * 128];
        bw2[nt][kt] = f;
      }
#pragma unroll
    for (int m = 0; m < 8; m++) {
      bf16x8 a0 = *(const bf16x8*)&hbuf[(m * 16 + cc) * HBS + qd * 8];
      bf16x8 a1 = *(const bf16x8*)&hbuf[(m * 16 + cc) * HBS + 32 + qd * 8];
      acc2[m][0] = MFMA(a0, bw2[0][0], acc2[m][0]);
      acc2[m][1] = MFMA(a0, bw2[1][0], acc2[m][1]);
      acc2[m][0] = MFMA(a1, bw2[0][1], acc2[m][0]);
      acc2[m][1] = MFMA(a1, bw2[1][1], acc2[m][1]);
    }
    __syncthreads();
  }

  // ---- h2 epilogue: activation, stash into sim buffer (reused) ----
#pragma unroll
  for (int m = 0; m < 8; m++)
#pragma unroll
    for (int nt = 0; nt < 2; nt++)
#pragma unroll
      for (int r = 0; r < 4; r++) {
        float v = acc2[m][nt][r] * BNS;
        sim[(m * 16 + qd * 4 + r) * SIMS + wv * 32 + nt * 16 + cc] = (__bf16)LRELU(v);
      }
  __syncthreads();

  // ---- Phase D: e[j] = sigmoid(h2[j,:].w3 + b3) * ep_row[j] ----
  {
    const int j = tid >> 1;
    const int c0 = (tid & 1) << 6;
    float s = 0.f;
#pragma unroll 16
    for (int c = 0; c < 64; c++) s += (float)sim[j * SIMS + c0 + c] * w3[c0 + c];
    red[tid] = s;
  }
  __syncthreads();
  if (tid < 128) {
    float s = red[2 * tid] + red[2 * tid + 1] + b3[0];
    float sg = 1.f / (1.f + expf(-s));
    e_row[tid] = sg * ep_row[tid];
  }
  __syncthreads();  // protect red[] reads above from overwrite below

  // ---- Phase E: ep_sum, top-k, l1norm, +eye, row-normalize ----
  if (tid < 128) red[tid] = ep_row[tid];
  __syncthreads();
#pragma unroll
  for (int s = 64; s > 0; s >>= 1) { if (tid < s) red[tid] += red[tid + s]; __syncthreads(); }
  const float ep_sum = red[0];
  __syncthreads();

  if (tid < 128) {
    float v = e_row[tid];
    if (kval > 0) {  // stable rank-count == jax.lax.top_k (lower index wins ties)
      int cnt = 0;
      for (int jj = 0; jj < 128; jj++) {
        float u = e_row[jj];
        cnt += (u > v || (u == v && jj < tid)) ? 1 : 0;
      }
      e_m[tid] = (cnt < kval) ? v : 0.f;
    } else {
      e_m[tid] = v;
    }
  }
  __syncthreads();
  if (tid < 128) red[tid] = e_m[tid];
  __syncthreads();
#pragma unroll
  for (int s = 64; s > 0; s >>= 1) { if (tid < s) red[tid] += red[tid + s]; __syncthreads(); }
  const float l1 = red[0];
  __syncthreads();

  const float scale = ep_sum / fmaxf(l1, 1e-12f);
  float val = 0.f;
  if (tid < 128) {
    val = e_m[tid] * scale + ((tid == i) ? 1.f : 0.f) + 1e-6f;
    red[tid] = val;
  }
  __syncthreads();
#pragma unroll
  for (int s = 64; s > 0; s >>= 1) { if (tid < s) red[tid] += red[tid + s]; __syncthreads(); }
  const float rsum = red[0];
  __syncthreads();

  if (tid < 128) {
    float o = val / rsum;
    ep[rowoff + tid] = o;
    if (outp) outp[rowoff + tid] = o;
  }
}

// ---------------------------------------------------------------------------
// k_qk: q = vp@wq, k = vp@wk. One WG per (b,i); threads 0-127 -> q, 128-255 -> k.
// ---------------------------------------------------------------------------
__global__ __launch_bounds__(256) void k_qk(const float* __restrict__ vp,
                                            const float* __restrict__ wq,
                                            const float* __restrict__ wk,
                                            float* __restrict__ qo,
                                            float* __restrict__ ko) {
  __shared__ float vr[128];
  const int t = threadIdx.x;
  const size_t rowoff = ((size_t)blockIdx.x) << 7;
  if (t < 128) vr[t] = vp[rowoff + t];
  __syncthreads();
  const int o = t & 127;
  const float* w = (t < 128) ? wq : wk;
  float a = 0.f;
#pragma unroll 8
  for (int c = 0; c < 128; c++) a += vr[c] * w[c * 128 + o];
  float* dst = (t < 128) ? qo : ko;
  dst[rowoff + o] = a;
}

// ---------------------------------------------------------------------------
// k_attn_edge: per (b,i): 4-head softmax attention row (mean over heads),
// then edge = l1norm(ep * attn * (1-eye)) over j.
// ---------------------------------------------------------------------------
__global__ __launch_bounds__(128) void k_attn_edge(const float* __restrict__ qv,
                                                   const float* __restrict__ kv,
                                                   const float* __restrict__ ep,
                                                   float* __restrict__ eg) {
  __shared__ float qi[128];
  __shared__ float buf[128];
  const int j = threadIdx.x;
  const int b = blockIdx.x >> 7, i = blockIdx.x & 127;
  const size_t rowoff = ((size_t)blockIdx.x) << 7;
  qi[j] = qv[rowoff + j];
  __syncthreads();
  const float* krow = kv + (((size_t)(b * 128 + j)) << 7);
  float asum = 0.f;
#pragma unroll
  for (int h = 0; h < 4; h++) {
    float s = 0.f;
#pragma unroll
    for (int d = 0; d < 32; d += 4) {
      float4 kk = *(const float4*)(krow + h * 32 + d);
      s += qi[h * 32 + d] * kk.x + qi[h * 32 + d + 1] * kk.y +
           qi[h * 32 + d + 2] * kk.z + qi[h * 32 + d + 3] * kk.w;
    }
    s *= 0.17677669529663687f;  // 1/sqrt(32)
    buf[j] = s; __syncthreads();
    for (int t = 64; t > 0; t >>= 1) { if (j < t) buf[j] = fmaxf(buf[j], buf[j + t]); __syncthreads(); }
    float mx = buf[0]; __syncthreads();
    float e = expf(s - mx);
    buf[j] = e; __syncthreads();
    for (int t = 64; t > 0; t >>= 1) { if (j < t) buf[j] += buf[j + t]; __syncthreads(); }
    float Z = buf[0]; __syncthreads();
    asum += e / Z;
  }
  float attn = 0.25f * asum;
  float eraw = (j == i) ? 0.f : ep[rowoff + j] * attn;
  buf[j] = eraw; __syncthreads();
  for (int t = 64; t > 0; t >>= 1) { if (j < t) buf[j] += buf[j + t]; __syncthreads(); }
  float l1 = buf[0];
  eg[rowoff + j] = eraw / fmaxf(l1, 1e-12f);
}

// ---------------------------------------------------------------------------
// k_d2p: per (b,i): aggr = edge_row @ vp_b ; nf = [vp_i, aggr];
// vp_out_i = lrelu(bn(lrelu(bn(nf@w1))@w2))
// ---------------------------------------------------------------------------
__global__ __launch_bounds__(256) void k_d2p(const float* __restrict__ vp_in,
                                             const float* __restrict__ eg,
                                             const float* __restrict__ w1,
                                             const float* __restrict__ w2,
                                             float* __restrict__ vp_out) {
  __shared__ float er[128];
  __shared__ float nf[256];
  __shared__ float hb[256];
  const int t = threadIdx.x;
  const int b = blockIdx.x >> 7;
  const size_t rowoff = ((size_t)blockIdx.x) << 7;
  const float* vpb = vp_in + ((size_t)b << 14);
  if (t < 128) { er[t] = eg[rowoff + t]; nf[t] = vp_in[rowoff + t]; }
  __syncthreads();
  if (t >= 128) {
    const int c = t - 128;
    float a = 0.f;
#pragma unroll 8
    for (int jj = 0; jj < 128; jj++) a += er[jj] * vpb[(jj << 7) + c];
    nf[128 + c] = a;
  }
  __syncthreads();
  {
    float hv = 0.f;
#pragma unroll 8
    for (int c2 = 0; c2 < 256; c2++) hv += nf[c2] * w1[c2 * 256 + t];
    hv *= BNS;
    hb[t] = LRELU(hv);
  }
  __syncthreads();
  if (t < 128) {
    float ov = 0.f;
#pragma unroll 8
    for (int o = 0; o < 256; o++) ov += hb[o] * w2[o * 128 + t];
    ov *= BNS;
    vp_out[rowoff + t] = LRELU(ov);
  }
}

// ---------------------------------------------------------------------------
extern "C" void kernel_launch(void* const* d_in, const int* in_sizes, int n_in,
                              void* d_out, int out_size, void* d_ws, size_t ws_size,
                              hipStream_t stream) {
  const float* vp0    = (const float*)d_in[0];
  const float* ep0    = (const float*)d_in[1];
  const float* pre_w1 = (const float*)d_in[2];
  const float* pre_w2 = (const float*)d_in[3];
  const float* pre_w3 = (const float*)d_in[4];
  const float* pre_b3 = (const float*)d_in[5];
  const float* ps_w1  = (const float*)d_in[6];
  const float* ps_w2  = (const float*)d_in[7];
  const float* ps_w3  = (const float*)d_in[8];
  const float* ps_b3  = (const float*)d_in[9];
  const float* dw1    = (const float*)d_in[10];
  const float* dw2    = (const float*)d_in[11];
  const float* mwq    = (const float*)d_in[12];
  const float* mwk    = (const float*)d_in[13];

  char* ws = (char*)d_ws;
  float* ep  = (float*)(ws);                        // 512 KB
  float* vpb = (float*)(ws + (512ull << 10));       // 512 KB (gen0 d2p out)
  float* vpa = (float*)(ws + (1024ull << 10));      // 512 KB (gen1 d2p out)
  float* qf  = (float*)(ws + (1536ull << 10));      // 512 KB
  float* kf  = (float*)(ws + (2048ull << 10));      // 512 KB
  float* eg  = (float*)(ws + (2560ull << 10));      // 512 KB
  float* outp = (float*)d_out;

  k_init<<<512, 256, 0, stream>>>(ep0, ep);

  // pre-psim (no top-k)
  k_psim<<<1024, 256, 0, stream>>>(vp0, ep, pre_w1, pre_w2, pre_w3, pre_b3, 0, nullptr);

  // generation 0 (kval = int(128*0.9) = 115)
  k_qk<<<1024, 256, 0, stream>>>(vp0, mwq, mwk, qf, kf);
  k_attn_edge<<<1024, 128, 0, stream>>>(qf, kf, ep, eg);
  k_d2p<<<1024, 256, 0, stream>>>(vp0, eg, dw1, dw2, vpb);
  k_psim<<<1024, 256, 0, stream>>>(vpb, ep, ps_w1, ps_w2, ps_w3, ps_b3, 115, nullptr);

  // generation 1 (kval = int(128*0.8) = 102)
  k_qk<<<1024, 256, 0, stream>>>(vpb, mwq + 16384, mwk + 16384, qf, kf);
  k_attn_edge<<<1024, 128, 0, stream>>>(qf, kf, ep, eg);
  k_d2p<<<1024, 256, 0, stream>>>(vpb, eg, dw1 + 65536, dw2 + 32768, vpa);
  k_psim<<<1024, 256, 0, stream>>>(vpa, ep, ps_w1 + 32768, ps_w2 + 32768,
                                   ps_w3 + 128, ps_b3 + 1, 102, outp);
}

// Round 3
// 268.734 us; speedup vs baseline: 1.2129x; 1.2129x over previous
//
#include <hip/hip_runtime.h>

typedef __bf16 bf16x8 __attribute__((ext_vector_type(8)));
typedef float floatx4 __attribute__((ext_vector_type(4)));

#define MFMA(a, b, c) __builtin_amdgcn_mfma_f32_16x16x32_bf16(a, b, c, 0, 0, 0)

#define BNS 0.9999950000374997f  /* 1/sqrt(1+1e-5) */
#define LRELU(x) ((x) > 0.f ? (x) : 0.01f * (x))

__device__ inline float wave_sum(float v) {
#pragma unroll
  for (int s = 32; s > 0; s >>= 1) v += __shfl_xor(v, s, 64);
  return v;
}
__device__ inline float wave_max(float v) {
#pragma unroll
  for (int s = 32; s > 0; s >>= 1) v = fmaxf(v, __shfl_xor(v, s, 64));
  return v;
}

// ---------------------------------------------------------------------------
// k_prep: swizzle the 3 psim weight sets (pre, g0, g1) into fragment-ordered
// bf16 so k_psim B-fragment loads are single coalesced 16B vector loads.
// w1b layout: [set][qtr4][kt4][wv4][ln64][jj8]; w2b: [set][qtr4][nt2][kt2][wv4][ln64][jj8]
// 24576 threads total (96 blocks x 256): first 12288 -> w1, rest -> w2.
// ---------------------------------------------------------------------------
__global__ __launch_bounds__(256) void k_prep(const float* __restrict__ pre_w1,
                                              const float* __restrict__ ps_w1,
                                              const float* __restrict__ pre_w2,
                                              const float* __restrict__ ps_w2,
                                              __bf16* __restrict__ w1b,
                                              __bf16* __restrict__ w2b) {
  const int tt = blockIdx.x * 256 + threadIdx.x;
  const int buf = tt / 12288;
  const int r = tt % 12288;
  const int set = r >> 12;
  const int q = r & 4095;
  const int ln = q & 63, qd = ln >> 4, cc = ln & 15;
  const int wv = (q >> 6) & 3;
  bf16x8 v;
  if (buf == 0) {
    const int kt = (q >> 8) & 3, qtr = (q >> 10) & 3;
    const float* src = (set == 0) ? pre_w1 : ps_w1 + (size_t)(set - 1) * 32768;
    const float* p = src + (size_t)(kt * 32 + qd * 8) * 256 + qtr * 64 + wv * 16 + cc;
#pragma unroll
    for (int jj = 0; jj < 8; jj++) v[jj] = (__bf16)p[jj * 256];
    *(bf16x8*)&w1b[(size_t)set * 32768 + q * 8] = v;
  } else {
    const int kt = (q >> 8) & 1, nt = (q >> 9) & 1, qtr = (q >> 10) & 3;
    const float* src = (set == 0) ? pre_w2 : ps_w2 + (size_t)(set - 1) * 32768;
    const float* p = src + (size_t)(qtr * 64 + kt * 32 + qd * 8) * 128 + wv * 32 + nt * 16 + cc;
#pragma unroll
    for (int jj = 0; jj < 8; jj++) v[jj] = (__bf16)p[jj * 128];
    *(bf16x8*)&w2b[(size_t)set * 32768 + q * 8] = v;
  }
}

// ---------------------------------------------------------------------------
// k_psim: one WG per (b,i) row. Fragment-major LDS layouts (conflict-free
// lane-contiguous b128), pre-swizzled bf16 weights, wave-shuffle reductions.
// ---------------------------------------------------------------------------
__global__ void __launch_bounds__(256, 3)
k_psim(const float* __restrict__ vp, const float* __restrict__ ep_in,
       float* __restrict__ ep_out,
       const __bf16* __restrict__ w1b, const __bf16* __restrict__ w2b,
       const float* __restrict__ w3, const float* __restrict__ b3,
       int kval, float* __restrict__ outp) {
  __shared__ __bf16 simf[16384];  // [kt4][m8][ln64][8]; reused for h2 frags [seg4][m8][ln64][8]
  __shared__ __bf16 hbf[8192];    // [h2][m8][ln64][8]  (one 64-col quarter of h1)
  __shared__ float ep_row[128];
  __shared__ float e_row[128];
  __shared__ float w3s[128];
  __shared__ float red[256];
  __shared__ float red2[4];

  const int tid = threadIdx.x;
  const int b = blockIdx.x >> 7, i = blockIdx.x & 127;
  const float* vpb = vp + ((size_t)b << 14);
  const float* vpi = vpb + (i << 7);
  const size_t rowoff = ((size_t)blockIdx.x) << 7;

  // ---- Phase A: sim features straight into fragment-major LDS ----
  {
    const int j = tid >> 1;
    const int c0 = (tid & 1) << 6;
    const int m = j >> 4, ccr = j & 15;
    const float* vpj = vpb + (j << 7) + c0;
    const float* vpx = vpi + c0;
#pragma unroll
    for (int c = 0; c < 64; c += 8) {
      const int gc = c0 + c;
      const int kt = gc >> 5, qdw = (gc >> 3) & 3;
      float4 a0 = *(const float4*)(vpj + c);
      float4 a1 = *(const float4*)(vpj + c + 4);
      float4 b0 = *(const float4*)(vpx + c);
      float4 b1 = *(const float4*)(vpx + c + 4);
      bf16x8 t;
      float d;
      d = a0.x - b0.x; t[0] = (__bf16)(d * d);
      d = a0.y - b0.y; t[1] = (__bf16)(d * d);
      d = a0.z - b0.z; t[2] = (__bf16)(d * d);
      d = a0.w - b0.w; t[3] = (__bf16)(d * d);
      d = a1.x - b1.x; t[4] = (__bf16)(d * d);
      d = a1.y - b1.y; t[5] = (__bf16)(d * d);
      d = a1.z - b1.z; t[6] = (__bf16)(d * d);
      d = a1.w - b1.w; t[7] = (__bf16)(d * d);
      *(bf16x8*)&simf[(((kt << 3) + m) << 6 | (qdw << 4 | ccr)) << 3] = t;
    }
    if (tid < 128) {
      ep_row[tid] = (tid == i) ? 0.f : ep_in[rowoff + tid];
      w3s[tid] = w3[tid];
    }
  }
  __syncthreads();

  const int wv = tid >> 6;   // wave 0..3
  const int ln = tid & 63;
  const int qd = ln >> 4;    // quad 0..3
  const int cc = ln & 15;

  floatx4 acc2[8][2];
#pragma unroll
  for (int m = 0; m < 8; m++) {
    acc2[m][0] = (floatx4){0.f, 0.f, 0.f, 0.f};
    acc2[m][1] = (floatx4){0.f, 0.f, 0.f, 0.f};
  }

  // h1-store decomposition for this lane (col = wv*16+cc within 64-quarter)
  const int h1h = wv >> 1;
  const int h1qd = ((wv & 1) << 1) | (cc >> 3);
  const int h1jj = cc & 7;

  // ---- MLP: four 64-col quarters; matmul2 accumulates across quarters ----
  for (int qtr = 0; qtr < 4; qtr++) {
    bf16x8 bw[4];
#pragma unroll
    for (int kt = 0; kt < 4; kt++)
      bw[kt] = *(const bf16x8*)&w1b[((((qtr * 4 + kt) * 4 + wv) * 64) + ln) * 8];
#pragma unroll
    for (int m2 = 0; m2 < 8; m2 += 2) {
      bf16x8 af0[4], af1[4];
#pragma unroll
      for (int kt = 0; kt < 4; kt++) {
        af0[kt] = *(const bf16x8*)&simf[(((kt << 3) + m2) << 6 | ln) << 3];
        af1[kt] = *(const bf16x8*)&simf[(((kt << 3) + m2 + 1) << 6 | ln) << 3];
      }
      floatx4 x0 = (floatx4){0.f, 0.f, 0.f, 0.f};
      floatx4 x1 = (floatx4){0.f, 0.f, 0.f, 0.f};
#pragma unroll
      for (int kt = 0; kt < 4; kt++) {
        x0 = MFMA(af0[kt], bw[kt], x0);
        x1 = MFMA(af1[kt], bw[kt], x1);
      }
#pragma unroll
      for (int r = 0; r < 4; r++) {
        float v0 = x0[r] * BNS;
        float v1 = x1[r] * BNS;
        hbf[(((h1h * 8 + m2) * 64) + h1qd * 16 + qd * 4 + r) * 8 + h1jj] = (__bf16)LRELU(v0);
        hbf[(((h1h * 8 + m2 + 1) * 64) + h1qd * 16 + qd * 4 + r) * 8 + h1jj] = (__bf16)LRELU(v1);
      }
    }
    __syncthreads();

    bf16x8 bw2[2][2];
#pragma unroll
    for (int nt = 0; nt < 2; nt++)
#pragma unroll
      for (int kt = 0; kt < 2; kt++)
        bw2[nt][kt] = *(const bf16x8*)&w2b[(((((qtr * 2 + nt) * 2 + kt) * 4 + wv) * 64) + ln) * 8];
#pragma unroll
    for (int m = 0; m < 8; m++) {
      bf16x8 a0 = *(const bf16x8*)&hbf[((m << 6) | ln) << 3];
      bf16x8 a1 = *(const bf16x8*)&hbf[(((8 + m) << 6) | ln) << 3];
      acc2[m][0] = MFMA(a0, bw2[0][0], acc2[m][0]);
      acc2[m][1] = MFMA(a0, bw2[1][0], acc2[m][1]);
      acc2[m][0] = MFMA(a1, bw2[0][1], acc2[m][0]);
      acc2[m][1] = MFMA(a1, bw2[1][1], acc2[m][1]);
    }
    __syncthreads();
  }

  // ---- h2 epilogue: activation, stash into simf as [seg4][m8][ln][8] ----
  {
    const int seg = wv;                       // col = wv*32 + nt*16 + cc -> col>>5 == wv
#pragma unroll
    for (int m = 0; m < 8; m++)
#pragma unroll
      for (int nt = 0; nt < 2; nt++) {
        const int q2 = (nt << 1) | (cc >> 3);
#pragma unroll
        for (int r = 0; r < 4; r++) {
          float v = acc2[m][nt][r] * BNS;
          simf[(((seg * 8 + m) * 64) + q2 * 16 + qd * 4 + r) * 8 + (cc & 7)] = (__bf16)LRELU(v);
        }
      }
  }
  __syncthreads();

  // ---- Phase D: e[j] = sigmoid(h2[j,:].w3 + b3) * ep_row[j] (vectorized) ----
  {
    const int j = tid & 127, hh = tid >> 7;
    const int m = j >> 4, R = j & 15;
    float s = 0.f;
#pragma unroll
    for (int sg = 0; sg < 2; sg++) {
      const int seg = hh * 2 + sg;
#pragma unroll
      for (int q3 = 0; q3 < 4; q3++) {
        bf16x8 f = *(const bf16x8*)&simf[(((seg * 8 + m) * 64) + q3 * 16 + R) * 8];
        const float* wp = &w3s[seg * 32 + q3 * 8];
#pragma unroll
        for (int jj = 0; jj < 8; jj++) s += (float)f[jj] * wp[jj];
      }
    }
    red[tid] = s;
  }
  __syncthreads();
  if (tid < 128) {
    float s = red[tid] + red[tid + 128] + b3[0];
    float sg = 1.f / (1.f + expf(-s));
    e_row[tid] = sg * ep_row[tid];
  }
  __syncthreads();

  // ---- Phase E: ep_sum, top-k (rank count, 2 halves), l1norm, normalize ----
  {
    float v = (tid < 128) ? ep_row[tid] : 0.f;
    float w = wave_sum(v);
    if (ln == 0) red2[wv] = w;
  }
  __syncthreads();
  const float ep_sum = red2[0] + red2[1];

  if (kval > 0) {
    const int j = tid & 127, hh = tid >> 7;
    const float v = e_row[j];
    int cnt = 0;
    const int base = hh << 6;
#pragma unroll 8
    for (int jj = 0; jj < 64; jj++) {
      float u = e_row[base + jj];
      cnt += (u > v || (u == v && (base + jj) < j)) ? 1 : 0;
    }
    red[tid] = (float)cnt;
  }
  __syncthreads();

  float em = 0.f;
  if (tid < 128) {
    float v = e_row[tid];
    if (kval > 0) {
      int cnt = (int)red[tid] + (int)red[tid + 128];
      em = (cnt < kval) ? v : 0.f;
    } else {
      em = v;
    }
  }
  {
    float w = wave_sum((tid < 128) ? em : 0.f);
    if (ln == 0) red2[wv] = w;
  }
  __syncthreads();
  const float l1 = red2[0] + red2[1];
  __syncthreads();

  const float scale = ep_sum / fmaxf(l1, 1e-12f);
  float val = 0.f;
  if (tid < 128) val = em * scale + ((tid == i) ? 1.f : 0.f) + 1e-6f;
  {
    float w = wave_sum((tid < 128) ? val : 0.f);
    if (ln == 0) red2[wv] = w;
  }
  __syncthreads();
  const float rsum = red2[0] + red2[1];

  if (tid < 128) {
    float o = val / rsum;
    ep_out[rowoff + tid] = o;
    if (outp) outp[rowoff + tid] = o;
  }
}

// ---------------------------------------------------------------------------
// k_qk: q = vp@wq, k = vp@wk. One WG per (b,i); threads 0-127 -> q, 128-255 -> k.
// ---------------------------------------------------------------------------
__global__ __launch_bounds__(256) void k_qk(const float* __restrict__ vp,
                                            const float* __restrict__ wq,
                                            const float* __restrict__ wk,
                                            float* __restrict__ qo,
                                            float* __restrict__ ko) {
  __shared__ float vr[128];
  const int t = threadIdx.x;
  const size_t rowoff = ((size_t)blockIdx.x) << 7;
  if (t < 128) vr[t] = vp[rowoff + t];
  __syncthreads();
  const int o = t & 127;
  const float* w = (t < 128) ? wq : wk;
  float a = 0.f;
#pragma unroll 8
  for (int c = 0; c < 128; c++) a += vr[c] * w[c * 128 + o];
  float* dst = (t < 128) ? qo : ko;
  dst[rowoff + o] = a;
}

// ---------------------------------------------------------------------------
// k_attn_d2p: fused per (b,i): 4-head softmax attn row (2 heads/thread-half),
// edge = l1norm(ep*attn*(1-eye)), aggr = edge@vp, 2-layer MLP -> vp_out row.
// ---------------------------------------------------------------------------
__global__ __launch_bounds__(256) void k_attn_d2p(const float* __restrict__ qv,
                                                  const float* __restrict__ kv,
                                                  const float* __restrict__ ep,
                                                  const float* __restrict__ vp_in,
                                                  const float* __restrict__ w1,
                                                  const float* __restrict__ w2,
                                                  float* __restrict__ vp_out) {
  __shared__ float qi[128];
  __shared__ float sbuf[512];   // [head][j]
  __shared__ float er[128];
  __shared__ float nf[256];
  __shared__ float hb[256];
  __shared__ float red2[4];

  const int tid = threadIdx.x;
  const int wv = tid >> 6, ln = tid & 63;
  const int j = tid & 127, hh = tid >> 7;
  const int b = blockIdx.x >> 7, i = blockIdx.x & 127;
  const size_t rowoff = ((size_t)blockIdx.x) << 7;
  const float* vpbb = vp_in + ((size_t)b << 14);

  if (tid < 128) qi[tid] = qv[rowoff + tid];
  __syncthreads();

  // scores for two heads per thread
  {
    const float* krow = kv + (((size_t)(b * 128 + j)) << 7);
    const int h0 = hh * 2, h1 = hh * 2 + 1;
    float s0 = 0.f, s1 = 0.f;
#pragma unroll
    for (int d = 0; d < 32; d += 4) {
      float4 k0 = *(const float4*)(krow + h0 * 32 + d);
      float4 k1 = *(const float4*)(krow + h1 * 32 + d);
      s0 += qi[h0 * 32 + d] * k0.x + qi[h0 * 32 + d + 1] * k0.y +
            qi[h0 * 32 + d + 2] * k0.z + qi[h0 * 32 + d + 3] * k0.w;
      s1 += qi[h1 * 32 + d] * k1.x + qi[h1 * 32 + d + 1] * k1.y +
            qi[h1 * 32 + d + 2] * k1.z + qi[h1 * 32 + d + 3] * k1.w;
    }
    sbuf[h0 * 128 + j] = s0 * 0.17677669529663687f;
    sbuf[h1 * 128 + j] = s1 * 0.17677669529663687f;
  }
  __syncthreads();

  // per-head softmax: group g (64 threads) handles head g
  {
    const int g = tid >> 6;
    float a = sbuf[g * 128 + ln];
    float bv = sbuf[g * 128 + ln + 64];
    float mx = wave_max(fmaxf(a, bv));
    float e0 = expf(a - mx), e1 = expf(bv - mx);
    float Z = wave_sum(e0 + e1);
    sbuf[g * 128 + ln] = e0 / Z;
    sbuf[g * 128 + ln + 64] = e1 / Z;
  }
  __syncthreads();

  float eraw = 0.f;
  if (tid < 128) {
    float attn = 0.25f * (sbuf[j] + sbuf[128 + j] + sbuf[256 + j] + sbuf[384 + j]);
    eraw = (j == i) ? 0.f : ep[rowoff + j] * attn;
  }
  {
    float w = wave_sum((tid < 128) ? eraw : 0.f);
    if (ln == 0) red2[wv] = w;
  }
  __syncthreads();
  const float l1 = red2[0] + red2[1];
  if (tid < 128) {
    er[j] = eraw / fmaxf(l1, 1e-12f);
    nf[j] = vp_in[rowoff + j];
  }
  __syncthreads();

  if (tid >= 128) {
    const int c = tid - 128;
    float a = 0.f;
#pragma unroll 8
    for (int jj = 0; jj < 128; jj++) a += er[jj] * vpbb[(jj << 7) + c];
    nf[128 + c] = a;
  }
  __syncthreads();
  {
    float hv = 0.f;
#pragma unroll 8
    for (int c2 = 0; c2 < 256; c2++) hv += nf[c2] * w1[c2 * 256 + tid];
    hv *= BNS;
    hb[tid] = LRELU(hv);
  }
  __syncthreads();
  if (tid < 128) {
    float ov = 0.f;
#pragma unroll 8
    for (int o = 0; o < 256; o++) ov += hb[o] * w2[o * 128 + tid];
    ov *= BNS;
    vp_out[rowoff + tid] = LRELU(ov);
  }
}

// ---------------------------------------------------------------------------
extern "C" void kernel_launch(void* const* d_in, const int* in_sizes, int n_in,
                              void* d_out, int out_size, void* d_ws, size_t ws_size,
                              hipStream_t stream) {
  const float* vp0    = (const float*)d_in[0];
  const float* ep0    = (const float*)d_in[1];
  const float* pre_w1 = (const float*)d_in[2];
  const float* pre_w2 = (const float*)d_in[3];
  const float* pre_w3 = (const float*)d_in[4];
  const float* pre_b3 = (const float*)d_in[5];
  const float* ps_w1  = (const float*)d_in[6];
  const float* ps_w2  = (const float*)d_in[7];
  const float* ps_w3  = (const float*)d_in[8];
  const float* ps_b3  = (const float*)d_in[9];
  const float* dw1    = (const float*)d_in[10];
  const float* dw2    = (const float*)d_in[11];
  const float* mwq    = (const float*)d_in[12];
  const float* mwk    = (const float*)d_in[13];

  char* ws = (char*)d_ws;
  float* ep   = (float*)(ws);                      // 512 KB
  float* vpb  = (float*)(ws + (512ull << 10));     // 512 KB
  float* vpa  = (float*)(ws + (1024ull << 10));    // 512 KB
  float* qf   = (float*)(ws + (1536ull << 10));    // 512 KB
  float* kf   = (float*)(ws + (2048ull << 10));    // 512 KB
  __bf16* w1b = (__bf16*)(ws + (2560ull << 10));   // 192 KB (3 sets)
  __bf16* w2b = (__bf16*)(ws + (2560ull << 10) + 196608);  // 192 KB
  float* outp = (float*)d_out;

  k_prep<<<96, 256, 0, stream>>>(pre_w1, ps_w1, pre_w2, ps_w2, w1b, w2b);

  // pre-psim (no top-k): reads ep0 input directly, writes ep working buffer
  k_psim<<<1024, 256, 0, stream>>>(vp0, ep0, ep, w1b, w2b, pre_w3, pre_b3, 0, nullptr);

  // generation 0 (kval = 115)
  k_qk<<<1024, 256, 0, stream>>>(vp0, mwq, mwk, qf, kf);
  k_attn_d2p<<<1024, 256, 0, stream>>>(qf, kf, ep, vp0, dw1, dw2, vpb);
  k_psim<<<1024, 256, 0, stream>>>(vpb, ep, ep, w1b + 32768, w2b + 32768,
                                   ps_w3, ps_b3, 115, nullptr);

  // generation 1 (kval = 102)
  k_qk<<<1024, 256, 0, stream>>>(vpb, mwq + 16384, mwk + 16384, qf, kf);
  k_attn_d2p<<<1024, 256, 0, stream>>>(qf, kf, ep, vpb, dw1 + 65536, dw2 + 32768, vpa);
  k_psim<<<1024, 256, 0, stream>>>(vpa, ep, ep, w1b + 65536, w2b + 65536,
                                   ps_w3 + 128, ps_b3 + 1, 102, outp);
}

// Round 4
// 231.335 us; speedup vs baseline: 1.4090x; 1.1617x over previous
//
#include <hip/hip_runtime.h>

typedef __bf16 bf16x8 __attribute__((ext_vector_type(8)));
typedef float floatx4 __attribute__((ext_vector_type(4)));

#define MFMA(a, b, c) __builtin_amdgcn_mfma_f32_16x16x32_bf16(a, b, c, 0, 0, 0)

#define BNS 0.9999950000374997f  /* 1/sqrt(1+1e-5) */
#define LRELU(x) ((x) > 0.f ? (x) : 0.01f * (x))

__device__ inline float wave_sum(float v) {
#pragma unroll
  for (int s = 32; s > 0; s >>= 1) v += __shfl_xor(v, s, 64);
  return v;
}
__device__ inline float wave_max(float v) {
#pragma unroll
  for (int s = 32; s > 0; s >>= 1) v = fmaxf(v, __shfl_xor(v, s, 64));
  return v;
}

// ---------------------------------------------------------------------------
// k_prep: one-shot weight swizzles.
//  tt <  24576 : psim w1/w2 -> MFMA-fragment-ordered bf16 (3 sets)
//  tt <  40960 : d2p w1 [2][256,256] -> interleaved bf16x8  d1i[gen][cb32][o256][8]
//  tt <  49152 : d2p w2 [2][256,128] -> interleaved bf16x8  d2i[gen][kb32][o128][8]
//  tt <  57344 : mha wq/wk [2][128,128] -> qki[gen][qk2][cb16][o128][8]
// ---------------------------------------------------------------------------
__global__ __launch_bounds__(256) void k_prep(const float* __restrict__ pre_w1,
                                              const float* __restrict__ ps_w1,
                                              const float* __restrict__ pre_w2,
                                              const float* __restrict__ ps_w2,
                                              const float* __restrict__ dw1,
                                              const float* __restrict__ dw2,
                                              const float* __restrict__ mwq,
                                              const float* __restrict__ mwk,
                                              __bf16* __restrict__ w1b,
                                              __bf16* __restrict__ w2b,
                                              __bf16* __restrict__ d1i,
                                              __bf16* __restrict__ d2i,
                                              __bf16* __restrict__ qki) {
  const int tt = blockIdx.x * 256 + threadIdx.x;
  bf16x8 v;
  if (tt < 24576) {
    const int buf = tt / 12288;
    const int r = tt % 12288;
    const int set = r >> 12;
    const int q = r & 4095;
    const int ln = q & 63, qd = ln >> 4, cc = ln & 15;
    const int wv = (q >> 6) & 3;
    if (buf == 0) {
      const int kt = (q >> 8) & 3, qtr = (q >> 10) & 3;
      const float* src = (set == 0) ? pre_w1 : ps_w1 + (size_t)(set - 1) * 32768;
      const float* p = src + (size_t)(kt * 32 + qd * 8) * 256 + qtr * 64 + wv * 16 + cc;
#pragma unroll
      for (int jj = 0; jj < 8; jj++) v[jj] = (__bf16)p[jj * 256];
      *(bf16x8*)&w1b[(size_t)set * 32768 + q * 8] = v;
    } else {
      const int kt = (q >> 8) & 1, nt = (q >> 9) & 1, qtr = (q >> 10) & 3;
      const float* src = (set == 0) ? pre_w2 : ps_w2 + (size_t)(set - 1) * 32768;
      const float* p = src + (size_t)(qtr * 64 + kt * 32 + qd * 8) * 128 + wv * 32 + nt * 16 + cc;
#pragma unroll
      for (int jj = 0; jj < 8; jj++) v[jj] = (__bf16)p[jj * 128];
      *(bf16x8*)&w2b[(size_t)set * 32768 + q * 8] = v;
    }
  } else if (tt < 40960) {
    const int u = tt - 24576;
    const int gen = u >> 13, r = u & 8191, cb = r >> 8, o = r & 255;
    const float* src = dw1 + (size_t)gen * 65536 + (size_t)(cb * 8) * 256 + o;
#pragma unroll
    for (int jj = 0; jj < 8; jj++) v[jj] = (__bf16)src[jj * 256];
    *(bf16x8*)&d1i[(size_t)(((gen * 32 + cb) * 256 + o)) * 8] = v;
  } else if (tt < 49152) {
    const int u = tt - 40960;
    const int gen = u >> 12, r = u & 4095, kb = r >> 7, o = r & 127;
    const float* src = dw2 + (size_t)gen * 32768 + (size_t)(kb * 8) * 128 + o;
#pragma unroll
    for (int jj = 0; jj < 8; jj++) v[jj] = (__bf16)src[jj * 128];
    *(bf16x8*)&d2i[(size_t)(((gen * 32 + kb) * 128 + o)) * 8] = v;
  } else if (tt < 57344) {
    const int u = tt - 49152;
    const int gen = u >> 12, r = u & 4095, qk = r >> 11, r2 = r & 2047;
    const int cb = r2 >> 7, o = r2 & 127;
    const float* src = (qk ? mwk : mwq) + (size_t)gen * 16384 + (size_t)(cb * 8) * 128 + o;
#pragma unroll
    for (int jj = 0; jj < 8; jj++) v[jj] = (__bf16)src[jj * 128];
    *(bf16x8*)&qki[(size_t)((((gen * 2 + qk) * 16 + cb) * 128 + o)) * 8] = v;
  }
}

// ---------------------------------------------------------------------------
// k_psim: UNCHANGED from round 3 (passed; re-profile with clean top-5 next).
// ---------------------------------------------------------------------------
__global__ void __launch_bounds__(256, 3)
k_psim(const float* __restrict__ vp, const float* __restrict__ ep_in,
       float* __restrict__ ep_out,
       const __bf16* __restrict__ w1b, const __bf16* __restrict__ w2b,
       const float* __restrict__ w3, const float* __restrict__ b3,
       int kval, float* __restrict__ outp) {
  __shared__ __bf16 simf[16384];
  __shared__ __bf16 hbf[8192];
  __shared__ float ep_row[128];
  __shared__ float e_row[128];
  __shared__ float w3s[128];
  __shared__ float red[256];
  __shared__ float red2[4];

  const int tid = threadIdx.x;
  const int b = blockIdx.x >> 7, i = blockIdx.x & 127;
  const float* vpb = vp + ((size_t)b << 14);
  const float* vpi = vpb + (i << 7);
  const size_t rowoff = ((size_t)blockIdx.x) << 7;

  {
    const int j = tid >> 1;
    const int c0 = (tid & 1) << 6;
    const int m = j >> 4, ccr = j & 15;
    const float* vpj = vpb + (j << 7) + c0;
    const float* vpx = vpi + c0;
#pragma unroll
    for (int c = 0; c < 64; c += 8) {
      const int gc = c0 + c;
      const int kt = gc >> 5, qdw = (gc >> 3) & 3;
      float4 a0 = *(const float4*)(vpj + c);
      float4 a1 = *(const float4*)(vpj + c + 4);
      float4 b0 = *(const float4*)(vpx + c);
      float4 b1 = *(const float4*)(vpx + c + 4);
      bf16x8 t;
      float d;
      d = a0.x - b0.x; t[0] = (__bf16)(d * d);
      d = a0.y - b0.y; t[1] = (__bf16)(d * d);
      d = a0.z - b0.z; t[2] = (__bf16)(d * d);
      d = a0.w - b0.w; t[3] = (__bf16)(d * d);
      d = a1.x - b1.x; t[4] = (__bf16)(d * d);
      d = a1.y - b1.y; t[5] = (__bf16)(d * d);
      d = a1.z - b1.z; t[6] = (__bf16)(d * d);
      d = a1.w - b1.w; t[7] = (__bf16)(d * d);
      *(bf16x8*)&simf[(((kt << 3) + m) << 6 | (qdw << 4 | ccr)) << 3] = t;
    }
    if (tid < 128) {
      ep_row[tid] = (tid == i) ? 0.f : ep_in[rowoff + tid];
      w3s[tid] = w3[tid];
    }
  }
  __syncthreads();

  const int wv = tid >> 6;
  const int ln = tid & 63;
  const int qd = ln >> 4;
  const int cc = ln & 15;

  floatx4 acc2[8][2];
#pragma unroll
  for (int m = 0; m < 8; m++) {
    acc2[m][0] = (floatx4){0.f, 0.f, 0.f, 0.f};
    acc2[m][1] = (floatx4){0.f, 0.f, 0.f, 0.f};
  }

  const int h1h = wv >> 1;
  const int h1qd = ((wv & 1) << 1) | (cc >> 3);
  const int h1jj = cc & 7;

  for (int qtr = 0; qtr < 4; qtr++) {
    bf16x8 bw[4];
#pragma unroll
    for (int kt = 0; kt < 4; kt++)
      bw[kt] = *(const bf16x8*)&w1b[((((qtr * 4 + kt) * 4 + wv) * 64) + ln) * 8];
#pragma unroll
    for (int m2 = 0; m2 < 8; m2 += 2) {
      bf16x8 af0[4], af1[4];
#pragma unroll
      for (int kt = 0; kt < 4; kt++) {
        af0[kt] = *(const bf16x8*)&simf[(((kt << 3) + m2) << 6 | ln) << 3];
        af1[kt] = *(const bf16x8*)&simf[(((kt << 3) + m2 + 1) << 6 | ln) << 3];
      }
      floatx4 x0 = (floatx4){0.f, 0.f, 0.f, 0.f};
      floatx4 x1 = (floatx4){0.f, 0.f, 0.f, 0.f};
#pragma unroll
      for (int kt = 0; kt < 4; kt++) {
        x0 = MFMA(af0[kt], bw[kt], x0);
        x1 = MFMA(af1[kt], bw[kt], x1);
      }
#pragma unroll
      for (int r = 0; r < 4; r++) {
        float v0 = x0[r] * BNS;
        float v1 = x1[r] * BNS;
        hbf[(((h1h * 8 + m2) * 64) + h1qd * 16 + qd * 4 + r) * 8 + h1jj] = (__bf16)LRELU(v0);
        hbf[(((h1h * 8 + m2 + 1) * 64) + h1qd * 16 + qd * 4 + r) * 8 + h1jj] = (__bf16)LRELU(v1);
      }
    }
    __syncthreads();

    bf16x8 bw2[2][2];
#pragma unroll
    for (int nt = 0; nt < 2; nt++)
#pragma unroll
      for (int kt = 0; kt < 2; kt++)
        bw2[nt][kt] = *(const bf16x8*)&w2b[(((((qtr * 2 + nt) * 2 + kt) * 4 + wv) * 64) + ln) * 8];
#pragma unroll
    for (int m = 0; m < 8; m++) {
      bf16x8 a0 = *(const bf16x8*)&hbf[((m << 6) | ln) << 3];
      bf16x8 a1 = *(const bf16x8*)&hbf[(((8 + m) << 6) | ln) << 3];
      acc2[m][0] = MFMA(a0, bw2[0][0], acc2[m][0]);
      acc2[m][1] = MFMA(a0, bw2[1][0], acc2[m][1]);
      acc2[m][0] = MFMA(a1, bw2[0][1], acc2[m][0]);
      acc2[m][1] = MFMA(a1, bw2[1][1], acc2[m][1]);
    }
    __syncthreads();
  }

  {
    const int seg = wv;
#pragma unroll
    for (int m = 0; m < 8; m++)
#pragma unroll
      for (int nt = 0; nt < 2; nt++) {
        const int q2 = (nt << 1) | (cc >> 3);
#pragma unroll
        for (int r = 0; r < 4; r++) {
          float v = acc2[m][nt][r] * BNS;
          simf[(((seg * 8 + m) * 64) + q2 * 16 + qd * 4 + r) * 8 + (cc & 7)] = (__bf16)LRELU(v);
        }
      }
  }
  __syncthreads();

  {
    const int j = tid & 127, hh = tid >> 7;
    const int m = j >> 4, R = j & 15;
    float s = 0.f;
#pragma unroll
    for (int sg = 0; sg < 2; sg++) {
      const int seg = hh * 2 + sg;
#pragma unroll
      for (int q3 = 0; q3 < 4; q3++) {
        bf16x8 f = *(const bf16x8*)&simf[(((seg * 8 + m) * 64) + q3 * 16 + R) * 8];
        const float* wp = &w3s[seg * 32 + q3 * 8];
#pragma unroll
        for (int jj = 0; jj < 8; jj++) s += (float)f[jj] * wp[jj];
      }
    }
    red[tid] = s;
  }
  __syncthreads();
  if (tid < 128) {
    float s = red[tid] + red[tid + 128] + b3[0];
    float sg = 1.f / (1.f + expf(-s));
    e_row[tid] = sg * ep_row[tid];
  }
  __syncthreads();

  {
    float v = (tid < 128) ? ep_row[tid] : 0.f;
    float w = wave_sum(v);
    if (ln == 0) red2[wv] = w;
  }
  __syncthreads();
  const float ep_sum = red2[0] + red2[1];

  if (kval > 0) {
    const int j = tid & 127, hh = tid >> 7;
    const float v = e_row[j];
    int cnt = 0;
    const int base = hh << 6;
#pragma unroll 8
    for (int jj = 0; jj < 64; jj++) {
      float u = e_row[base + jj];
      cnt += (u > v || (u == v && (base + jj) < j)) ? 1 : 0;
    }
    red[tid] = (float)cnt;
  }
  __syncthreads();

  float em = 0.f;
  if (tid < 128) {
    float v = e_row[tid];
    if (kval > 0) {
      int cnt = (int)red[tid] + (int)red[tid + 128];
      em = (cnt < kval) ? v : 0.f;
    } else {
      em = v;
    }
  }
  {
    float w = wave_sum((tid < 128) ? em : 0.f);
    if (ln == 0) red2[wv] = w;
  }
  __syncthreads();
  const float l1 = red2[0] + red2[1];
  __syncthreads();

  const float scale = ep_sum / fmaxf(l1, 1e-12f);
  float val = 0.f;
  if (tid < 128) val = em * scale + ((tid == i) ? 1.f : 0.f) + 1e-6f;
  {
    float w = wave_sum((tid < 128) ? val : 0.f);
    if (ln == 0) red2[wv] = w;
  }
  __syncthreads();
  const float rsum = red2[0] + red2[1];

  if (tid < 128) {
    float o = val / rsum;
    ep_out[rowoff + tid] = o;
    if (outp) outp[rowoff + tid] = o;
  }
}

// ---------------------------------------------------------------------------
// k_qk v2: interleaved bf16x8 weights -> 16 coalesced 16B loads per thread.
// ---------------------------------------------------------------------------
__global__ __launch_bounds__(256) void k_qk(const float* __restrict__ vp,
                                            const __bf16* __restrict__ qkw,
                                            float* __restrict__ qo,
                                            float* __restrict__ ko) {
  __shared__ float vr[128];
  const int t = threadIdx.x;
  const size_t rowoff = ((size_t)blockIdx.x) << 7;
  if (t < 128) vr[t] = vp[rowoff + t];
  __syncthreads();
  const int o = t & 127;
  const __bf16* base = qkw + ((t >> 7) ? 16384 : 0);
  const float4* vr4 = (const float4*)vr;
  float a = 0.f;
#pragma unroll
  for (int cb = 0; cb < 16; cb++) {
    bf16x8 w8 = *(const bf16x8*)&base[(cb * 128 + o) * 8];
    float4 v0 = vr4[2 * cb], v1 = vr4[2 * cb + 1];
    a += v0.x * (float)w8[0] + v0.y * (float)w8[1] + v0.z * (float)w8[2] + v0.w * (float)w8[3] +
         v1.x * (float)w8[4] + v1.y * (float)w8[5] + v1.z * (float)w8[6] + v1.w * (float)w8[7];
  }
  float* dst = (t < 128) ? qo : ko;
  dst[rowoff + o] = a;
}

// ---------------------------------------------------------------------------
// k_attn_d2p v2: 2 rows (i, i+1) per block, grid 512. Fused attn row softmax,
// edge l1norm, aggr (float4), 2-layer MLP with interleaved bf16x8 weights.
// ---------------------------------------------------------------------------
__global__ __launch_bounds__(256) void k_attn_d2p(const float* __restrict__ qv,
                                                  const float* __restrict__ kv,
                                                  const float* __restrict__ ep,
                                                  const float* __restrict__ vp_in,
                                                  const __bf16* __restrict__ d1,
                                                  const __bf16* __restrict__ d2,
                                                  float* __restrict__ vp_out) {
  __shared__ float qi[256];      // [row2][128]
  __shared__ float sbuf[1024];   // [row2][head4][j128]
  __shared__ float er[256];      // [row2][128]
  __shared__ float nf[512];      // [row2][256]
  __shared__ float hb[512];      // [row2][256]
  __shared__ float pbuf[2048];   // [row2][jg8][c128]
  __shared__ float red2[4];

  const int tid = threadIdx.x;
  const int wv = tid >> 6, ln = tid & 63;
  const int b = blockIdx.x >> 6;
  const int r0 = (blockIdx.x & 63) * 2;
  const size_t rowoff0 = ((size_t)(b * 128 + r0)) << 7;
  const float* vpbb = vp_in + ((size_t)b << 14);

  qi[tid] = qv[rowoff0 + tid];   // rows r0, r0+1 contiguous
  __syncthreads();

  // scores: thread handles 2 heads x 2 rows for column j
  {
    const int j = tid & 127, hh = tid >> 7;
    const float* krow = kv + (((size_t)(b * 128 + j)) << 7);
    const int h0 = hh * 2, h1 = hh * 2 + 1;
    float s00 = 0.f, s01 = 0.f, s10 = 0.f, s11 = 0.f;
#pragma unroll
    for (int d = 0; d < 32; d += 4) {
      float4 k0 = *(const float4*)(krow + h0 * 32 + d);
      float4 k1 = *(const float4*)(krow + h1 * 32 + d);
      s00 += qi[h0 * 32 + d] * k0.x + qi[h0 * 32 + d + 1] * k0.y +
             qi[h0 * 32 + d + 2] * k0.z + qi[h0 * 32 + d + 3] * k0.w;
      s01 += qi[h1 * 32 + d] * k1.x + qi[h1 * 32 + d + 1] * k1.y +
             qi[h1 * 32 + d + 2] * k1.z + qi[h1 * 32 + d + 3] * k1.w;
      s10 += qi[128 + h0 * 32 + d] * k0.x + qi[128 + h0 * 32 + d + 1] * k0.y +
             qi[128 + h0 * 32 + d + 2] * k0.z + qi[128 + h0 * 32 + d + 3] * k0.w;
      s11 += qi[128 + h1 * 32 + d] * k1.x + qi[128 + h1 * 32 + d + 1] * k1.y +
             qi[128 + h1 * 32 + d + 2] * k1.z + qi[128 + h1 * 32 + d + 3] * k1.w;
    }
    const float sc = 0.17677669529663687f;
    sbuf[(0 * 4 + h0) * 128 + j] = s00 * sc;
    sbuf[(0 * 4 + h1) * 128 + j] = s01 * sc;
    sbuf[(1 * 4 + h0) * 128 + j] = s10 * sc;
    sbuf[(1 * 4 + h1) * 128 + j] = s11 * sc;
  }
  __syncthreads();

  // softmax: wave g handles head g, both rows
  {
    const int g = wv;
#pragma unroll
    for (int row = 0; row < 2; row++) {
      float a = sbuf[(row * 4 + g) * 128 + ln];
      float bb = sbuf[(row * 4 + g) * 128 + 64 + ln];
      float mx = wave_max(fmaxf(a, bb));
      float e0 = expf(a - mx), e1 = expf(bb - mx);
      float Z = wave_sum(e0 + e1);
      sbuf[(row * 4 + g) * 128 + ln] = e0 / Z;
      sbuf[(row * 4 + g) * 128 + 64 + ln] = e1 / Z;
    }
  }
  __syncthreads();

  // edge l1norm; waves 0-1 -> row 0, waves 2-3 -> row 1
  {
    const int row = tid >> 7, j = tid & 127;
    float attn = 0.25f * (sbuf[(row * 4) * 128 + j] + sbuf[(row * 4 + 1) * 128 + j] +
                          sbuf[(row * 4 + 2) * 128 + j] + sbuf[(row * 4 + 3) * 128 + j]);
    float eraw = (j == r0 + row) ? 0.f : ep[rowoff0 + tid] * attn;
    float w = wave_sum(eraw);
    if (ln == 0) red2[wv] = w;
    __syncthreads();
    float l1row = red2[row * 2] + red2[row * 2 + 1];
    er[tid] = eraw / fmaxf(l1row, 1e-12f);
    nf[(row << 8) + j] = vp_in[rowoff0 + tid];
  }
  __syncthreads();

  // aggr: thread (cg, jg): partial float4 over 16 j's, both rows
  {
    const int cg = tid & 31, jg = tid >> 5;
    float4 a0 = {0.f, 0.f, 0.f, 0.f}, a1 = {0.f, 0.f, 0.f, 0.f};
#pragma unroll
    for (int jj = 0; jj < 16; jj++) {
      const int j = jg * 16 + jj;
      float4 v = *(const float4*)(vpbb + (j << 7) + (cg << 2));
      float e0 = er[j], e1 = er[128 + j];
      a0.x += e0 * v.x; a0.y += e0 * v.y; a0.z += e0 * v.z; a0.w += e0 * v.w;
      a1.x += e1 * v.x; a1.y += e1 * v.y; a1.z += e1 * v.z; a1.w += e1 * v.w;
    }
    *(float4*)&pbuf[(jg * 32 + cg) * 4] = a0;
    *(float4*)&pbuf[1024 + (jg * 32 + cg) * 4] = a1;
  }
  __syncthreads();
  {
    const int row = tid >> 7, c = tid & 127;
    float s = 0.f;
#pragma unroll
    for (int jg = 0; jg < 8; jg++) s += pbuf[(row << 10) + jg * 128 + c];
    nf[(row << 8) + 128 + c] = s;
  }
  __syncthreads();

  // mlp1: thread -> row = tid>>7, outputs {o, o+128} for that row
  {
    const int row = tid >> 7, o = tid & 127;
    const float4* nfr4 = (const float4*)&nf[row << 8];
    float a0 = 0.f, a1 = 0.f;
#pragma unroll 4
    for (int cb = 0; cb < 32; cb++) {
      bf16x8 wa = *(const bf16x8*)&d1[(cb * 256 + o) * 8];
      bf16x8 wb = *(const bf16x8*)&d1[(cb * 256 + o + 128) * 8];
      float4 n0 = nfr4[2 * cb], n1 = nfr4[2 * cb + 1];
      a0 += n0.x * (float)wa[0] + n0.y * (float)wa[1] + n0.z * (float)wa[2] + n0.w * (float)wa[3] +
            n1.x * (float)wa[4] + n1.y * (float)wa[5] + n1.z * (float)wa[6] + n1.w * (float)wa[7];
      a1 += n0.x * (float)wb[0] + n0.y * (float)wb[1] + n0.z * (float)wb[2] + n0.w * (float)wb[3] +
            n1.x * (float)wb[4] + n1.y * (float)wb[5] + n1.z * (float)wb[6] + n1.w * (float)wb[7];
    }
    hb[(row << 8) + o] = LRELU(a0 * BNS);
    hb[(row << 8) + o + 128] = LRELU(a1 * BNS);
  }
  __syncthreads();

  // mlp2: thread -> row, output o; full K=256 per thread, coalesced store
  {
    const int row = tid >> 7, o = tid & 127;
    const float4* hbr4 = (const float4*)&hb[row << 8];
    float a = 0.f;
#pragma unroll 4
    for (int kb = 0; kb < 32; kb++) {
      bf16x8 w8 = *(const bf16x8*)&d2[(kb * 128 + o) * 8];
      float4 h0 = hbr4[2 * kb], h1 = hbr4[2 * kb + 1];
      a += h0.x * (float)w8[0] + h0.y * (float)w8[1] + h0.z * (float)w8[2] + h0.w * (float)w8[3] +
           h1.x * (float)w8[4] + h1.y * (float)w8[5] + h1.z * (float)w8[6] + h1.w * (float)w8[7];
    }
    vp_out[rowoff0 + tid] = LRELU(a * BNS);
  }
}

// ---------------------------------------------------------------------------
extern "C" void kernel_launch(void* const* d_in, const int* in_sizes, int n_in,
                              void* d_out, int out_size, void* d_ws, size_t ws_size,
                              hipStream_t stream) {
  const float* vp0    = (const float*)d_in[0];
  const float* ep0    = (const float*)d_in[1];
  const float* pre_w1 = (const float*)d_in[2];
  const float* pre_w2 = (const float*)d_in[3];
  const float* pre_w3 = (const float*)d_in[4];
  const float* pre_b3 = (const float*)d_in[5];
  const float* ps_w1  = (const float*)d_in[6];
  const float* ps_w2  = (const float*)d_in[7];
  const float* ps_w3  = (const float*)d_in[8];
  const float* ps_b3  = (const float*)d_in[9];
  const float* dw1    = (const float*)d_in[10];
  const float* dw2    = (const float*)d_in[11];
  const float* mwq    = (const float*)d_in[12];
  const float* mwk    = (const float*)d_in[13];

  char* ws = (char*)d_ws;
  float* ep   = (float*)(ws);                      // 512 KB
  float* vpb  = (float*)(ws + (512ull << 10));     // 512 KB
  float* vpa  = (float*)(ws + (1024ull << 10));    // 512 KB
  float* qf   = (float*)(ws + (1536ull << 10));    // 512 KB
  float* kf   = (float*)(ws + (2048ull << 10));    // 512 KB
  __bf16* w1b = (__bf16*)(ws + (2560ull << 10));            // 192 KB
  __bf16* w2b = (__bf16*)(ws + (2560ull << 10) + 196608);   // 192 KB
  __bf16* d1i = (__bf16*)(ws + (2560ull << 10) + 393216);   // 256 KB
  __bf16* d2i = (__bf16*)(ws + (2560ull << 10) + 655360);   // 128 KB
  __bf16* qki = (__bf16*)(ws + (2560ull << 10) + 786432);   // 128 KB
  float* outp = (float*)d_out;

  k_prep<<<224, 256, 0, stream>>>(pre_w1, ps_w1, pre_w2, ps_w2, dw1, dw2, mwq, mwk,
                                  w1b, w2b, d1i, d2i, qki);

  // pre-psim (no top-k)
  k_psim<<<1024, 256, 0, stream>>>(vp0, ep0, ep, w1b, w2b, pre_w3, pre_b3, 0, nullptr);

  // generation 0 (kval = 115)
  k_qk<<<1024, 256, 0, stream>>>(vp0, qki, qf, kf);
  k_attn_d2p<<<512, 256, 0, stream>>>(qf, kf, ep, vp0, d1i, d2i, vpb);
  k_psim<<<1024, 256, 0, stream>>>(vpb, ep, ep, w1b + 32768, w2b + 32768,
                                   ps_w3, ps_b3, 115, nullptr);

  // generation 1 (kval = 102)
  k_qk<<<1024, 256, 0, stream>>>(vpb, qki + 32768, qf, kf);
  k_attn_d2p<<<512, 256, 0, stream>>>(qf, kf, ep, vpb, d1i + 65536, d2i + 32768, vpa);
  k_psim<<<1024, 256, 0, stream>>>(vpa, ep, ep, w1b + 65536, w2b + 65536,
                                   ps_w3 + 128, ps_b3 + 1, 102, outp);
}